// Round 4
// baseline (330.630 us; speedup 1.0000x reference)
//
#include <hip/hip_runtime.h>
#include <hip/hip_bf16.h>
#include <stdint.h>

// ---------------------------------------------------------------------------
// MultiHeadAttention fused forward, MI355X (gfx950)
//   B=4, S=2048, D_MODEL=1024, H=16, depth=64; fp32 I/O, bf16 MFMA internal.
// R6 (GEMM rewrite: 256x128 multi-phase pipelined tiles):
//   - gemm256_core: BM=256, BN=128, BK=64, 8 waves (4Mx2N, wave-tile 64x64 --
//     same fragment/epilogue math as the proven 128^2 core). 96KB LDS double
//     buffer; 4 phases/K-tile {ds_read frags; stage half-prefetch; barrier;
//     setprio(1) 8xMFMA setprio(0); barrier}; single vmcnt(0) per K-tile,
//     placed ~3.5 phases after issue (loads fly under compute, never
//     drain-after-issue). Raw s_barrier throughout (no __syncthreads drain).
//   - grid 256 blocks/GEMM: qkv = 3 exact rounds, dense = 1; XCD-bijective
//     blockIdx swizzle (256%8==0).
//   - attention unchanged from R5 (81 us, bank-conflict-free).
// ---------------------------------------------------------------------------

#define SEQ    2048
#define DEPTH  64
#define HEADS  16
#define NMODEL 1024
#define MROWS  8192   // B*S

typedef __bf16 bf16x8 __attribute__((ext_vector_type(8)));
typedef float  f32x4  __attribute__((ext_vector_type(4)));

__device__ __forceinline__ unsigned short f32_bf16(float f) {
    union { float f; unsigned int u; } c; c.f = f;
    unsigned int u = c.u + 0x7FFFu + ((c.u >> 16) & 1u);   // RNE
    return (unsigned short)(u >> 16);
}

__device__ __forceinline__ void gload16(const unsigned short* g, unsigned short* l) {
    __builtin_amdgcn_global_load_lds(
        (const __attribute__((address_space(1))) unsigned int*)g,
        (__attribute__((address_space(3))) unsigned int*)l, 16, 0, 0);
}

// ---------------------------------------------------------------------------
__global__ __launch_bounds__(256) void cvt3_kernel(
    const float* __restrict__ a, const float* __restrict__ b, const float* __restrict__ c,
    unsigned short* __restrict__ oa, unsigned short* __restrict__ ob,
    unsigned short* __restrict__ oc, int n4)
{
    const float* in; unsigned short* out;
    if (blockIdx.y == 0) { in = a; out = oa; }
    else if (blockIdx.y == 1) { in = b; out = ob; }
    else { in = c; out = oc; }
    int i = blockIdx.x * 256 + threadIdx.x;
    if (i < n4) {
        float4 f = ((const float4*)in)[i];
        ushort4 o;
        o.x = f32_bf16(f.x); o.y = f32_bf16(f.y);
        o.z = f32_bf16(f.z); o.w = f32_bf16(f.w);
        ((ushort4*)out)[i] = o;
    }
}

__global__ __launch_bounds__(256) void cvt4_kernel(
    const float* __restrict__ a, const float* __restrict__ b,
    const float* __restrict__ c, const float* __restrict__ d,
    unsigned short* __restrict__ oa, unsigned short* __restrict__ ob,
    unsigned short* __restrict__ oc, unsigned short* __restrict__ od, int n4)
{
    const float* in; unsigned short* out;
    if (blockIdx.y == 0) { in = a; out = oa; }
    else if (blockIdx.y == 1) { in = b; out = ob; }
    else if (blockIdx.y == 2) { in = c; out = oc; }
    else { in = d; out = od; }
    int i = blockIdx.x * 256 + threadIdx.x;
    if (i < n4) {
        float4 f = ((const float4*)in)[i];
        ushort4 o;
        o.x = f32_bf16(f.x); o.y = f32_bf16(f.y);
        o.z = f32_bf16(f.z); o.w = f32_bf16(f.w);
        ((ushort4*)out)[i] = o;
    }
}

// ---------------------------------------------------------------------------
// 256x128 tile GEMM core, BK=64, XOR-swizzled LDS, 8 waves (4M x 2N).
// C[m,n] = sum_k A[m,k]*W[n,k]; K = 1024.
// mode 0: fp32 out row-major [.,NMODEL], bias[col]
// mode 1: bf16 out head-split [B,H,S,64], (acc+bias[col])*scale
// mode 2: bf16 out row-major [.,MROWS], bias[row]   (V^T), token order
//         permuted within 32-token groups: pi(k) = (k&3) + 4*((k>>4)&1)
//         + 8*((k>>2)&3)  -- matches attn's PV k-slot map.
__device__ __forceinline__ void gemm256_core(
    const unsigned short* __restrict__ A, const unsigned short* __restrict__ W,
    const float* __restrict__ bias, void* __restrict__ outp,
    int mode, float scale, int m0, int n0,
    unsigned short* __restrict__ Alds, unsigned short* __restrict__ Blds)
{
    const int tid  = threadIdx.x;
    const int wave = tid >> 6, lane = tid & 63;
    const int l15  = lane & 15, quad = lane >> 4;
    const int wr   = wave >> 1, wc = wave & 1;   // 4 m-waves x 2 n-waves
    const int swz  = l15 & 7;
    const int K    = 1024;

    f32x4 acc[4][4] = {};

    // staging: thread tid covers row trow of the sweep, swizzled source granule
    const int trow = tid >> 3;                       // 0..63
    const int tg   = ((tid & 7) ^ (trow & 7)) << 3;  // swizzled granule (shorts)
    const unsigned short* Asrc[2][2];                // [unit u][sweep s]
    const unsigned short* Bsrc[2];
    #pragma unroll
    for (int u = 0; u < 2; ++u) {
        #pragma unroll
        for (int s = 0; s < 2; ++s)
            Asrc[u][s] = A + (size_t)(m0 + u * 128 + s * 64 + trow) * K + tg;
        Bsrc[u] = W + (size_t)(n0 + u * 64 + trow) * K + tg;
    }

    // stage unit u of K-tile kt2 into buffer buf (A: 2 sweeps, B: 1 sweep)
    auto STAGE = [&](int buf, int kt2, int u) {
        gload16(Asrc[u][0] + kt2 * 64, Alds + buf * 16384 + (u * 128 + wave * 8) * 64);
        gload16(Asrc[u][1] + kt2 * 64, Alds + buf * 16384 + (u * 128 + 64 + wave * 8) * 64);
        gload16(Bsrc[u]    + kt2 * 64, Blds + buf * 8192  + (u * 64 + wave * 8) * 64);
    };

    STAGE(0, 0, 0);
    STAGE(0, 0, 1);
    asm volatile("s_waitcnt vmcnt(0)" ::: "memory");
    __builtin_amdgcn_s_barrier();

    for (int kt = 0; kt < 16; ++kt) {
        const int cur = kt & 1;
        const unsigned short* Ab = Alds + cur * 16384;
        const unsigned short* Bb = Blds + cur * 8192;
        const int arow = wr * 64 + l15;
        const int brow = wc * 64 + l15;
        const bool pre = (kt + 1 < 16);
        bf16x8 bfr[4], af0, af1;

        // ---- phase (kc=0, mh=0): read B + A(0,1); stage unit0 of kt+1 ----
        {
            const int pg = ((quad ^ swz) << 3);
            bfr[0] = *(const bf16x8*)&Bb[(brow)      * 64 + pg];
            bfr[1] = *(const bf16x8*)&Bb[(brow + 16) * 64 + pg];
            bfr[2] = *(const bf16x8*)&Bb[(brow + 32) * 64 + pg];
            bfr[3] = *(const bf16x8*)&Bb[(brow + 48) * 64 + pg];
            af0    = *(const bf16x8*)&Ab[(arow)      * 64 + pg];
            af1    = *(const bf16x8*)&Ab[(arow + 16) * 64 + pg];
            if (pre) STAGE(cur ^ 1, kt + 1, 0);
            __builtin_amdgcn_s_barrier();
            __builtin_amdgcn_s_setprio(1);
            #pragma unroll
            for (int j = 0; j < 4; ++j)
                acc[0][j] = __builtin_amdgcn_mfma_f32_16x16x32_bf16(af0, bfr[j], acc[0][j], 0, 0, 0);
            #pragma unroll
            for (int j = 0; j < 4; ++j)
                acc[1][j] = __builtin_amdgcn_mfma_f32_16x16x32_bf16(af1, bfr[j], acc[1][j], 0, 0, 0);
            __builtin_amdgcn_s_setprio(0);
            __builtin_amdgcn_s_barrier();
        }
        // ---- phase (kc=0, mh=1): read A(2,3); stage unit1 of kt+1 ----
        {
            const int pg = ((quad ^ swz) << 3);
            af0 = *(const bf16x8*)&Ab[(arow + 32) * 64 + pg];
            af1 = *(const bf16x8*)&Ab[(arow + 48) * 64 + pg];
            if (pre) STAGE(cur ^ 1, kt + 1, 1);
            __builtin_amdgcn_s_barrier();
            __builtin_amdgcn_s_setprio(1);
            #pragma unroll
            for (int j = 0; j < 4; ++j)
                acc[2][j] = __builtin_amdgcn_mfma_f32_16x16x32_bf16(af0, bfr[j], acc[2][j], 0, 0, 0);
            #pragma unroll
            for (int j = 0; j < 4; ++j)
                acc[3][j] = __builtin_amdgcn_mfma_f32_16x16x32_bf16(af1, bfr[j], acc[3][j], 0, 0, 0);
            __builtin_amdgcn_s_setprio(0);
            __builtin_amdgcn_s_barrier();
        }
        // ---- phase (kc=1, mh=0) ----
        {
            const int pg = (((4 + quad) ^ swz) << 3);
            bfr[0] = *(const bf16x8*)&Bb[(brow)      * 64 + pg];
            bfr[1] = *(const bf16x8*)&Bb[(brow + 16) * 64 + pg];
            bfr[2] = *(const bf16x8*)&Bb[(brow + 32) * 64 + pg];
            bfr[3] = *(const bf16x8*)&Bb[(brow + 48) * 64 + pg];
            af0    = *(const bf16x8*)&Ab[(arow)      * 64 + pg];
            af1    = *(const bf16x8*)&Ab[(arow + 16) * 64 + pg];
            __builtin_amdgcn_s_barrier();
            __builtin_amdgcn_s_setprio(1);
            #pragma unroll
            for (int j = 0; j < 4; ++j)
                acc[0][j] = __builtin_amdgcn_mfma_f32_16x16x32_bf16(af0, bfr[j], acc[0][j], 0, 0, 0);
            #pragma unroll
            for (int j = 0; j < 4; ++j)
                acc[1][j] = __builtin_amdgcn_mfma_f32_16x16x32_bf16(af1, bfr[j], acc[1][j], 0, 0, 0);
            __builtin_amdgcn_s_setprio(0);
            __builtin_amdgcn_s_barrier();
        }
        // ---- phase (kc=1, mh=1): vmcnt hand-off for kt+1's loads ----
        {
            const int pg = (((4 + quad) ^ swz) << 3);
            af0 = *(const bf16x8*)&Ab[(arow + 32) * 64 + pg];
            af1 = *(const bf16x8*)&Ab[(arow + 48) * 64 + pg];
            __builtin_amdgcn_s_barrier();
            __builtin_amdgcn_s_setprio(1);
            #pragma unroll
            for (int j = 0; j < 4; ++j)
                acc[2][j] = __builtin_amdgcn_mfma_f32_16x16x32_bf16(af0, bfr[j], acc[2][j], 0, 0, 0);
            #pragma unroll
            for (int j = 0; j < 4; ++j)
                acc[3][j] = __builtin_amdgcn_mfma_f32_16x16x32_bf16(af1, bfr[j], acc[3][j], 0, 0, 0);
            __builtin_amdgcn_s_setprio(0);
            asm volatile("s_waitcnt vmcnt(0)" ::: "memory");
            __builtin_amdgcn_s_barrier();
        }
    }

    #pragma unroll
    for (int i = 0; i < 4; ++i) {
        #pragma unroll
        for (int j = 0; j < 4; ++j) {
            const int col = n0 + wc * 64 + j * 16 + l15;
            const int row_b = m0 + wr * 64 + i * 16 + quad * 4;
            if (mode == 2) {
                // permuted token position within its 32-group
                const int colp = (col & ~31)
                               | (col & 3)
                               | (((col >> 4) & 1) << 2)
                               | (((col >> 2) & 3) << 3);
                #pragma unroll
                for (int r = 0; r < 4; ++r) {
                    const int row = row_b + r;
                    ((unsigned short*)outp)[(size_t)row * MROWS + colp] =
                        f32_bf16(acc[i][j][r] + bias[row]);
                }
            } else if (mode == 0) {
                const float bv = bias[col];
                #pragma unroll
                for (int r = 0; r < 4; ++r)
                    ((float*)outp)[(size_t)(row_b + r) * NMODEL + col] = acc[i][j][r] + bv;
            } else {
                const float bv = bias[col];
                const int h_ = col >> 6, d_ = col & 63;
                #pragma unroll
                for (int r = 0; r < 4; ++r) {
                    const int row = row_b + r;
                    const int b_ = row >> 11, s_ = row & 2047;
                    ((unsigned short*)outp)[(((size_t)(b_ * HEADS + h_) * SEQ + s_) << 6) + d_] =
                        f32_bf16((acc[i][j][r] + bv) * scale);
                }
            }
        }
    }
}

// QKV fused: grid (256, 3). z=0: Q (scaled), z=1: K, z=2: V^T (operands swapped)
__global__ __launch_bounds__(512, 2) void gemm_qkv(
    const unsigned short* __restrict__ qb,  const unsigned short* __restrict__ wqb,
    const float* __restrict__ bq, unsigned short* __restrict__ Qp,
    const unsigned short* __restrict__ kb,  const unsigned short* __restrict__ wkb,
    const float* __restrict__ bk, unsigned short* __restrict__ Kpj,
    const unsigned short* __restrict__ wvb, const unsigned short* __restrict__ vb,
    const float* __restrict__ bv, unsigned short* __restrict__ Vtg,
    float qscale)
{
    __shared__ unsigned short Alds[2 * 256 * 64];   // 64 KB
    __shared__ unsigned short Blds[2 * 128 * 64];   // 32 KB
    const int o = blockIdx.x, z = blockIdx.y;
    const int sid = (o & 7) * 32 + (o >> 3);        // XCD-bijective swizzle (256%8==0)
    if (z == 0) {
        gemm256_core(qb, wqb, bq, Qp, 1, qscale, (sid >> 3) * 256, (sid & 7) * 128, Alds, Blds);
    } else if (z == 1) {
        gemm256_core(kb, wkb, bk, Kpj, 1, 1.0f, (sid >> 3) * 256, (sid & 7) * 128, Alds, Blds);
    } else {
        // M = 1024 (weights rows, 4 m-blocks), N = 8192 (activation rows, 64 n-blocks)
        gemm256_core(wvb, vb, bv, Vtg, 2, 1.0f, (sid & 3) * 256, (sid >> 2) * 128, Alds, Blds);
    }
}

__global__ __launch_bounds__(512, 2) void gemm_dense(
    const unsigned short* __restrict__ A, const unsigned short* __restrict__ W,
    const float* __restrict__ bias, float* __restrict__ out)
{
    __shared__ unsigned short Alds[2 * 256 * 64];
    __shared__ unsigned short Blds[2 * 128 * 64];
    const int o = blockIdx.x;
    const int sid = (o & 7) * 32 + (o >> 3);
    gemm256_core(A, W, bias, out, 0, 1.0f, (sid >> 3) * 256, (sid & 7) * 128, Alds, Blds);
}

// ---------------------------------------------------------------------------
// Flash attention, S^T formulation, no-max softmax, register-resident P.
// Grid: (S/256, B*H). 4 waves; wave owns 64 q-rows. K-tiles of 64 keys,
// processed as two 32-key subtiles so softmax of subtile 0 overlaps QK^T of
// subtile 1. Double-buffered K/V LDS; 1 barrier per tile. (Unchanged from R5.)
//
// PV k-slot map: slot s = quad*8+j of the PV MFMA for subtile `half` carries
//   key k = 32*half + 16*(j>>2) + 4*quad + (j&3)
// P B-fragment = lane's own S^T registers (no LDS, no shuffles).
// Vtg's global token order is pre-permuted (pi above) so the V A-fragment is
// ONE swizzled ds_read_b128 at granule (half*4+quad)^swz -- same pattern as K.
__global__ __launch_bounds__(256, 2) void attn_fwd(
    const unsigned short* __restrict__ Qp,   // [B,H,S,64] bf16, pre-scaled
    const unsigned short* __restrict__ Kp,   // [B,H,S,64] bf16
    const unsigned short* __restrict__ Vtg,  // [H*64, B*S] bf16, token-permuted
    unsigned short* __restrict__ Op)         // [B*S,1024] bf16
{
    __shared__ unsigned short Klds[2 * 64 * 64];
    __shared__ unsigned short Vlds[2 * 64 * 64];
    const int tid  = threadIdx.x;
    const int wave = tid >> 6, lane = tid & 63;
    const int l15  = lane & 15, quad = lane >> 4;
    const int swz  = l15 & 7;
    const int bh   = blockIdx.y;
    const int b_   = bh >> 4, h_ = bh & 15;
    const int q0   = blockIdx.x * 256;

    const unsigned short* Qb = Qp + (size_t)bh * SEQ * DEPTH;
    const unsigned short* Kb = Kp + (size_t)bh * SEQ * DEPTH;
    const unsigned short* Vb = Vtg + (size_t)h_ * DEPTH * MROWS + (size_t)b_ * SEQ;

    const int srow = (wave << 3) + (lane >> 3);
    const int scg  = (lane & 7) ^ ((lane >> 3) & 7);   // swizzled source granule

    const unsigned short* Kg0 = Kb + (size_t)srow * DEPTH + scg * 8;
    const unsigned short* Kg1 = Kb + (size_t)(srow + 32) * DEPTH + scg * 8;
    const unsigned short* Vg0 = Vb + (size_t)srow * MROWS + scg * 8;
    const unsigned short* Vg1 = Vb + (size_t)(srow + 32) * MROWS + scg * 8;

    // Q B-fragments (persistent): lane holds Q[q=16i+l15][d=32kc+quad*8+j]
    bf16x8 qf[4][2];
    #pragma unroll
    for (int i = 0; i < 4; ++i)
        #pragma unroll
        for (int kc = 0; kc < 2; ++kc)
            qf[i][kc] = *(const bf16x8*)(Qb + (size_t)(q0 + wave * 64 + i * 16 + l15) * DEPTH
                                         + kc * 32 + quad * 8);

    // all-ones bf16 A-fragment for the l-sum MFMA
    union { bf16x8 v; unsigned short s[8]; } uo;
    #pragma unroll
    for (int j = 0; j < 8; ++j) uo.s[j] = 0x3F80;
    const bf16x8 ones = uo.v;

    f32x4 Ot[4][4] = {};
    f32x4 lacc[4]  = {};

    auto STAGE = [&](int buf, int kt) {
        unsigned short* KW = &Klds[buf * 4096 + wave * 512];
        unsigned short* VW = &Vlds[buf * 4096 + wave * 512];
        gload16(Kg0 + (size_t)kt * 4096, KW);
        gload16(Kg1 + (size_t)kt * 4096, KW + 2048);
        gload16(Vg0 + kt * 64, VW);
        gload16(Vg1 + kt * 64, VW + 2048);
    };

    STAGE(0, 0);
    asm volatile("s_waitcnt vmcnt(0)" ::: "memory");
    __builtin_amdgcn_s_barrier();

    for (int kt = 0; kt < SEQ / 64; ++kt) {
        const int cur = kt & 1;
        if (kt + 1 < SEQ / 64) STAGE(cur ^ 1, kt + 1);

        const unsigned short* Kc = &Klds[cur * 4096];

        // two 32-key subtiles; subtile `half` covers keys 64kt+32half..+31
        #pragma unroll
        for (int half = 0; half < 2; ++half) {
            // ---- QK^T MFMA cluster (keys 32half..32half+31) ----
            __builtin_amdgcn_s_setprio(1);
            const int r0 = (2 * half) * 16 + l15;
            const int r1 = (2 * half + 1) * 16 + l15;
            bf16x8 ka0 = *(const bf16x8*)&Kc[r0 * 64 + ((quad ^ swz) << 3)];
            bf16x8 ka1 = *(const bf16x8*)&Kc[r0 * 64 + (((4 + quad) ^ swz) << 3)];
            bf16x8 kb0 = *(const bf16x8*)&Kc[r1 * 64 + ((quad ^ swz) << 3)];
            bf16x8 kb1 = *(const bf16x8*)&Kc[r1 * 64 + (((4 + quad) ^ swz) << 3)];
            f32x4 S0[4], S1[4];
            #pragma unroll
            for (int i = 0; i < 4; ++i) {
                S0[i] = f32x4{};
                S0[i] = __builtin_amdgcn_mfma_f32_16x16x32_bf16(ka0, qf[i][0], S0[i], 0, 0, 0);
                S0[i] = __builtin_amdgcn_mfma_f32_16x16x32_bf16(ka1, qf[i][1], S0[i], 0, 0, 0);
                S1[i] = f32x4{};
                S1[i] = __builtin_amdgcn_mfma_f32_16x16x32_bf16(kb0, qf[i][0], S1[i], 0, 0, 0);
                S1[i] = __builtin_amdgcn_mfma_f32_16x16x32_bf16(kb1, qf[i][1], S1[i], 0, 0, 0);
            }
            __builtin_amdgcn_s_setprio(0);

            // ---- softmax: p = exp2(S), pack P B-fragments in-register ----
            bf16x8 pfh[4];
            #pragma unroll
            for (int i = 0; i < 4; ++i) {
                float e0 = __builtin_amdgcn_exp2f(S0[i][0]);
                float e1 = __builtin_amdgcn_exp2f(S0[i][1]);
                float e2 = __builtin_amdgcn_exp2f(S0[i][2]);
                float e3 = __builtin_amdgcn_exp2f(S0[i][3]);
                float e4 = __builtin_amdgcn_exp2f(S1[i][0]);
                float e5 = __builtin_amdgcn_exp2f(S1[i][1]);
                float e6 = __builtin_amdgcn_exp2f(S1[i][2]);
                float e7 = __builtin_amdgcn_exp2f(S1[i][3]);
                union { bf16x8 v; __hip_bfloat162 h[4]; } up;
                up.h[0] = __float22bfloat162_rn(make_float2(e0, e1));
                up.h[1] = __float22bfloat162_rn(make_float2(e2, e3));
                up.h[2] = __float22bfloat162_rn(make_float2(e4, e5));
                up.h[3] = __float22bfloat162_rn(make_float2(e6, e7));
                pfh[i] = up.v;
            }

            // ---- l-sum + PV MFMA cluster ----
            __builtin_amdgcn_s_setprio(1);
            lacc[0] = __builtin_amdgcn_mfma_f32_16x16x32_bf16(ones, pfh[0], lacc[0], 0, 0, 0);
            lacc[1] = __builtin_amdgcn_mfma_f32_16x16x32_bf16(ones, pfh[1], lacc[1], 0, 0, 0);
            lacc[2] = __builtin_amdgcn_mfma_f32_16x16x32_bf16(ones, pfh[2], lacc[2], 0, 0, 0);
            lacc[3] = __builtin_amdgcn_mfma_f32_16x16x32_bf16(ones, pfh[3], lacc[3], 0, 0, 0);
            #pragma unroll
            for (int dd = 0; dd < 4; ++dd) {
                bf16x8 vf = *(const bf16x8*)&Vlds[cur * 4096 +
                            (dd * 16 + l15) * 64 + (((half * 4 + quad) ^ swz) << 3)];
                #pragma unroll
                for (int i = 0; i < 4; ++i)
                    Ot[i][dd] = __builtin_amdgcn_mfma_f32_16x16x32_bf16(vf, pfh[i], Ot[i][dd], 0, 0, 0);
            }
            __builtin_amdgcn_s_setprio(0);
        }

        asm volatile("s_waitcnt vmcnt(0)" ::: "memory");
        __builtin_amdgcn_s_barrier();
    }

    // lacc[i][*] already holds the full denominator for q = i*16+l15
    #pragma unroll
    for (int i = 0; i < 4; ++i) {
        const float inv = 1.0f / lacc[i][0];
        const int row = b_ * SEQ + q0 + wave * 64 + i * 16 + l15;
        #pragma unroll
        for (int dd = 0; dd < 4; ++dd) {
            ushort4 ov;
            ov.x = f32_bf16(Ot[i][dd][0] * inv);
            ov.y = f32_bf16(Ot[i][dd][1] * inv);
            ov.z = f32_bf16(Ot[i][dd][2] * inv);
            ov.w = f32_bf16(Ot[i][dd][3] * inv);
            const int col = h_ * 64 + dd * 16 + quad * 4;
            *(ushort4*)&Op[(size_t)row * NMODEL + col] = ov;
        }
    }
}

// ---------------------------------------------------------------------------
extern "C" void kernel_launch(void* const* d_in, const int* in_sizes, int n_in,
                              void* d_out, int out_size, void* d_ws, size_t ws_size,
                              hipStream_t stream) {
    const float* q  = (const float*)d_in[0];
    const float* k  = (const float*)d_in[1];
    const float* v  = (const float*)d_in[2];
    const float* wq = (const float*)d_in[3];
    const float* bq = (const float*)d_in[4];
    const float* wk = (const float*)d_in[5];
    const float* bk = (const float*)d_in[6];
    const float* wv = (const float*)d_in[7];
    const float* bv = (const float*)d_in[8];
    const float* wd = (const float*)d_in[9];
    const float* bd = (const float*)d_in[10];

    char* ws = (char*)d_ws;
    size_t off = 0;
    auto alloc = [&](size_t bytes) { char* p = ws + off; off += bytes; return p; };
    const size_t ACT = (size_t)MROWS * NMODEL * 2;
    const size_t WGT = (size_t)NMODEL * NMODEL * 2;

    unsigned short* qb   = (unsigned short*)alloc(ACT);
    unsigned short* kb   = (unsigned short*)alloc(ACT);
    unsigned short* vb   = (unsigned short*)alloc(ACT);
    unsigned short* wqb  = (unsigned short*)alloc(WGT);
    unsigned short* wkb  = (unsigned short*)alloc(WGT);
    unsigned short* wvb  = (unsigned short*)alloc(WGT);
    unsigned short* wdb  = (unsigned short*)alloc(WGT);
    unsigned short* Qp   = (unsigned short*)alloc(ACT);
    unsigned short* Kpj  = (unsigned short*)alloc(ACT);
    unsigned short* Vtg  = (unsigned short*)alloc(ACT);   // [H*64, B*S], token-permuted
    unsigned short* attn = (unsigned short*)alloc(ACT);

    const int nAct4 = MROWS * NMODEL / 4;
    const int nWgt4 = NMODEL * NMODEL / 4;
    cvt3_kernel<<<dim3(nAct4 / 256, 3), 256, 0, stream>>>(q, k, v, qb, kb, vb, nAct4);
    cvt4_kernel<<<dim3(nWgt4 / 256, 4), 256, 0, stream>>>(wq, wk, wv, wd,
                                                          wqb, wkb, wvb, wdb, nWgt4);

    const float SC = 0.18033688011112042f;   // log2(e)/sqrt(64)
    gemm_qkv<<<dim3(256, 3), 512, 0, stream>>>(qb, wqb, bq, Qp,
                                               kb, wkb, bk, Kpj,
                                               wvb, vb, bv, Vtg, SC);

    attn_fwd<<<dim3(SEQ / 256, 64), 256, 0, stream>>>(Qp, Kpj, Vtg, attn);

    gemm_dense<<<256, 512, 0, stream>>>(attn, wdb, bd, (float*)d_out);
}

// Round 5
// 314.973 us; speedup vs baseline: 1.0497x; 1.0497x over previous
//
#include <hip/hip_runtime.h>
#include <hip/hip_bf16.h>
#include <stdint.h>

// ---------------------------------------------------------------------------
// MultiHeadAttention fused forward, MI355X (gfx950)
//   B=4, S=2048, D_MODEL=1024, H=16, depth=64; fp32 I/O, bf16 MFMA internal.
// R7 (GEMM schedule fix):
//   - gemm256_core: 256x128 tile, BK=64, 8 waves (4Mx2N, 64x64/wave).
//     3-buffer LDS (144 KB), 2-deep prefetch, counted s_waitcnt vmcnt(6)
//     (never drains in-loop), ONE barrier per K-tile, 32 MFMAs per barrier
//     interval, setprio(1) around MFMA clusters. This replaces R6's
//     8-barrier/drain-style schedule (the measured anti-pattern).
//   - cvt3+cvt4 merged into one dispatch (7 tensors, early-exit).
//   - attention unchanged from R5 (80 us, 0 bank conflicts).
// ---------------------------------------------------------------------------

#define SEQ    2048
#define DEPTH  64
#define HEADS  16
#define NMODEL 1024
#define MROWS  8192   // B*S

typedef __bf16 bf16x8 __attribute__((ext_vector_type(8)));
typedef float  f32x4  __attribute__((ext_vector_type(4)));

__device__ __forceinline__ unsigned short f32_bf16(float f) {
    union { float f; unsigned int u; } c; c.f = f;
    unsigned int u = c.u + 0x7FFFu + ((c.u >> 16) & 1u);   // RNE
    return (unsigned short)(u >> 16);
}

__device__ __forceinline__ void gload16(const unsigned short* g, unsigned short* l) {
    __builtin_amdgcn_global_load_lds(
        (const __attribute__((address_space(1))) unsigned int*)g,
        (__attribute__((address_space(3))) unsigned int*)l, 16, 0, 0);
}

// ---------------------------------------------------------------------------
// One dispatch converts all 7 fp32 tensors to bf16.
// y in [0,2]: activations (n4a float4 groups); y in [3,6]: weights (n4w).
__global__ __launch_bounds__(256) void cvt7_kernel(
    const float* __restrict__ a0, const float* __restrict__ a1, const float* __restrict__ a2,
    const float* __restrict__ w0, const float* __restrict__ w1,
    const float* __restrict__ w2, const float* __restrict__ w3,
    unsigned short* __restrict__ oa0, unsigned short* __restrict__ oa1,
    unsigned short* __restrict__ oa2,
    unsigned short* __restrict__ ow0, unsigned short* __restrict__ ow1,
    unsigned short* __restrict__ ow2, unsigned short* __restrict__ ow3,
    int n4a, int n4w)
{
    const float* in; unsigned short* out; int n4;
    switch (blockIdx.y) {
        case 0: in = a0; out = oa0; n4 = n4a; break;
        case 1: in = a1; out = oa1; n4 = n4a; break;
        case 2: in = a2; out = oa2; n4 = n4a; break;
        case 3: in = w0; out = ow0; n4 = n4w; break;
        case 4: in = w1; out = ow1; n4 = n4w; break;
        case 5: in = w2; out = ow2; n4 = n4w; break;
        default: in = w3; out = ow3; n4 = n4w; break;
    }
    int i = blockIdx.x * 256 + threadIdx.x;
    if (i < n4) {
        float4 f = ((const float4*)in)[i];
        ushort4 o;
        o.x = f32_bf16(f.x); o.y = f32_bf16(f.y);
        o.z = f32_bf16(f.z); o.w = f32_bf16(f.w);
        ((ushort4*)out)[i] = o;
    }
}

// ---------------------------------------------------------------------------
// 256x128 tile GEMM core, BK=64, XOR-swizzled LDS, 8 waves (4M x 2N).
// C[m,n] = sum_k A[m,k]*W[n,k]; K = 1024 (16 K-tiles).
// Pipeline: 3 LDS buffers, 2-deep prefetch, counted vmcnt(6), 1 barrier/tile.
// mode 0: fp32 out row-major [.,NMODEL], bias[col]
// mode 1: bf16 out head-split [B,H,S,64], (acc+bias[col])*scale
// mode 2: bf16 out row-major [.,MROWS], bias[row]   (V^T), token order
//         permuted within 32-token groups: pi(k) = (k&3) + 4*((k>>4)&1)
//         + 8*((k>>2)&3)  -- matches attn's PV k-slot map.
__device__ __forceinline__ void gemm256_core(
    const unsigned short* __restrict__ A, const unsigned short* __restrict__ W,
    const float* __restrict__ bias, void* __restrict__ outp,
    int mode, float scale, int m0, int n0,
    unsigned short* __restrict__ Alds, unsigned short* __restrict__ Blds)
{
    const int tid  = threadIdx.x;
    const int wave = tid >> 6, lane = tid & 63;
    const int l15  = lane & 15, quad = lane >> 4;
    const int wr   = wave >> 1, wc = wave & 1;   // 4 m-waves x 2 n-waves
    const int swz  = l15 & 7;
    const int K    = 1024;

    f32x4 acc[4][4] = {};

    // staging: thread tid covers row trow of each 64-row sweep, swizzled granule
    const int trow = tid >> 3;                       // 0..63
    const int tg   = ((tid & 7) ^ (trow & 7)) << 3;  // swizzled source granule (shorts)
    const unsigned short* Asrc[2][2];                // [unit u][sweep s]
    const unsigned short* Bsrc[2];
    #pragma unroll
    for (int u = 0; u < 2; ++u) {
        #pragma unroll
        for (int s = 0; s < 2; ++s)
            Asrc[u][s] = A + (size_t)(m0 + u * 128 + s * 64 + trow) * K + tg;
        Bsrc[u] = W + (size_t)(n0 + u * 64 + trow) * K + tg;
    }

    // stage K-tile kt2 into buffer buf: 6 global_load_lds per lane-group
    auto STAGE = [&](int buf, int kt2) {
        unsigned short* Ad = Alds + buf * 16384;
        unsigned short* Bd = Blds + buf * 8192;
        gload16(Asrc[0][0] + kt2 * 64, Ad + (      wave * 8) * 64);
        gload16(Asrc[0][1] + kt2 * 64, Ad + ( 64 + wave * 8) * 64);
        gload16(Asrc[1][0] + kt2 * 64, Ad + (128 + wave * 8) * 64);
        gload16(Asrc[1][1] + kt2 * 64, Ad + (192 + wave * 8) * 64);
        gload16(Bsrc[0]    + kt2 * 64, Bd + (      wave * 8) * 64);
        gload16(Bsrc[1]    + kt2 * 64, Bd + ( 64 + wave * 8) * 64);
    };

    STAGE(0, 0);
    STAGE(1, 1);
    asm volatile("s_waitcnt vmcnt(6)" ::: "memory");   // tile0 resident, tile1 in flight
    __builtin_amdgcn_s_barrier();

    const int arow = wr * 64 + l15;
    const int brow = wc * 64 + l15;

    for (int kt = 0; kt < 16; ++kt) {
        const unsigned short* Ab = Alds + (kt % 3) * 16384;
        const unsigned short* Bb = Blds + (kt % 3) * 8192;

        // kc=0 fragments
        bf16x8 a0[4], b0[4];
        {
            const int pg = ((quad ^ swz) << 3);
            #pragma unroll
            for (int j = 0; j < 4; ++j)
                b0[j] = *(const bf16x8*)&Bb[(brow + j * 16) * 64 + pg];
            #pragma unroll
            for (int i = 0; i < 4; ++i)
                a0[i] = *(const bf16x8*)&Ab[(arow + i * 16) * 64 + pg];
        }
        // issue next-next tile's loads under this tile's compute
        if (kt + 2 < 16) STAGE((kt + 2) % 3, kt + 2);

        __builtin_amdgcn_s_setprio(1);
        #pragma unroll
        for (int i = 0; i < 4; ++i)
            #pragma unroll
            for (int j = 0; j < 4; ++j)
                acc[i][j] = __builtin_amdgcn_mfma_f32_16x16x32_bf16(a0[i], b0[j], acc[i][j], 0, 0, 0);
        __builtin_amdgcn_s_setprio(0);

        // kc=1 fragments (reads overlap the kc=0 MFMA cluster above)
        bf16x8 a1[4], b1[4];
        {
            const int pg = (((4 + quad) ^ swz) << 3);
            #pragma unroll
            for (int j = 0; j < 4; ++j)
                b1[j] = *(const bf16x8*)&Bb[(brow + j * 16) * 64 + pg];
            #pragma unroll
            for (int i = 0; i < 4; ++i)
                a1[i] = *(const bf16x8*)&Ab[(arow + i * 16) * 64 + pg];
        }
        __builtin_amdgcn_s_setprio(1);
        #pragma unroll
        for (int i = 0; i < 4; ++i)
            #pragma unroll
            for (int j = 0; j < 4; ++j)
                acc[i][j] = __builtin_amdgcn_mfma_f32_16x16x32_bf16(a1[i], b1[j], acc[i][j], 0, 0, 0);
        __builtin_amdgcn_s_setprio(0);

        // counted hand-off: next tile's 6 loads must be done; keep 6 in flight
        if (kt + 2 < 16)
            asm volatile("s_waitcnt vmcnt(6)" ::: "memory");
        else
            asm volatile("s_waitcnt vmcnt(0)" ::: "memory");
        __builtin_amdgcn_s_barrier();
    }

    #pragma unroll
    for (int i = 0; i < 4; ++i) {
        #pragma unroll
        for (int j = 0; j < 4; ++j) {
            const int col = n0 + wc * 64 + j * 16 + l15;
            const int row_b = m0 + wr * 64 + i * 16 + quad * 4;
            if (mode == 2) {
                // permuted token position within its 32-group
                const int colp = (col & ~31)
                               | (col & 3)
                               | (((col >> 4) & 1) << 2)
                               | (((col >> 2) & 3) << 3);
                #pragma unroll
                for (int r = 0; r < 4; ++r) {
                    const int row = row_b + r;
                    ((unsigned short*)outp)[(size_t)row * MROWS + colp] =
                        f32_bf16(acc[i][j][r] + bias[row]);
                }
            } else if (mode == 0) {
                const float bv = bias[col];
                #pragma unroll
                for (int r = 0; r < 4; ++r)
                    ((float*)outp)[(size_t)(row_b + r) * NMODEL + col] = acc[i][j][r] + bv;
            } else {
                const float bv = bias[col];
                const int h_ = col >> 6, d_ = col & 63;
                #pragma unroll
                for (int r = 0; r < 4; ++r) {
                    const int row = row_b + r;
                    const int b_ = row >> 11, s_ = row & 2047;
                    ((unsigned short*)outp)[(((size_t)(b_ * HEADS + h_) * SEQ + s_) << 6) + d_] =
                        f32_bf16((acc[i][j][r] + bv) * scale);
                }
            }
        }
    }
}

// QKV fused: grid (256, 3). z=0: Q (scaled), z=1: K, z=2: V^T (operands swapped)
__global__ __launch_bounds__(512, 2) void gemm_qkv(
    const unsigned short* __restrict__ qb,  const unsigned short* __restrict__ wqb,
    const float* __restrict__ bq, unsigned short* __restrict__ Qp,
    const unsigned short* __restrict__ kb,  const unsigned short* __restrict__ wkb,
    const float* __restrict__ bk, unsigned short* __restrict__ Kpj,
    const unsigned short* __restrict__ wvb, const unsigned short* __restrict__ vb,
    const float* __restrict__ bv, unsigned short* __restrict__ Vtg,
    float qscale)
{
    __shared__ unsigned short Alds[3 * 256 * 64];   // 96 KB
    __shared__ unsigned short Blds[3 * 128 * 64];   // 48 KB
    const int o = blockIdx.x, z = blockIdx.y;
    const int sid = (o & 7) * 32 + (o >> 3);        // XCD-bijective swizzle (256%8==0)
    if (z == 0) {
        gemm256_core(qb, wqb, bq, Qp, 1, qscale, (sid >> 3) * 256, (sid & 7) * 128, Alds, Blds);
    } else if (z == 1) {
        gemm256_core(kb, wkb, bk, Kpj, 1, 1.0f, (sid >> 3) * 256, (sid & 7) * 128, Alds, Blds);
    } else {
        // M = 1024 (weights rows, 4 m-blocks), N = 8192 (activation rows, 64 n-blocks)
        gemm256_core(wvb, vb, bv, Vtg, 2, 1.0f, (sid & 3) * 256, (sid >> 2) * 128, Alds, Blds);
    }
}

__global__ __launch_bounds__(512, 2) void gemm_dense(
    const unsigned short* __restrict__ A, const unsigned short* __restrict__ W,
    const float* __restrict__ bias, float* __restrict__ out)
{
    __shared__ unsigned short Alds[3 * 256 * 64];
    __shared__ unsigned short Blds[3 * 128 * 64];
    const int o = blockIdx.x;
    const int sid = (o & 7) * 32 + (o >> 3);
    gemm256_core(A, W, bias, out, 0, 1.0f, (sid >> 3) * 256, (sid & 7) * 128, Alds, Blds);
}

// ---------------------------------------------------------------------------
// Flash attention, S^T formulation, no-max softmax, register-resident P.
// Grid: (S/256, B*H). 4 waves; wave owns 64 q-rows. K-tiles of 64 keys,
// processed as two 32-key subtiles so softmax of subtile 0 overlaps QK^T of
// subtile 1. Double-buffered K/V LDS; 1 barrier per tile. (Unchanged from R5.)
//
// PV k-slot map: slot s = quad*8+j of the PV MFMA for subtile `half` carries
//   key k = 32*half + 16*(j>>2) + 4*quad + (j&3)
// P B-fragment = lane's own S^T registers (no LDS, no shuffles).
// Vtg's global token order is pre-permuted (pi above) so the V A-fragment is
// ONE swizzled ds_read_b128 at granule (half*4+quad)^swz -- same pattern as K.
__global__ __launch_bounds__(256, 2) void attn_fwd(
    const unsigned short* __restrict__ Qp,   // [B,H,S,64] bf16, pre-scaled
    const unsigned short* __restrict__ Kp,   // [B,H,S,64] bf16
    const unsigned short* __restrict__ Vtg,  // [H*64, B*S] bf16, token-permuted
    unsigned short* __restrict__ Op)         // [B*S,1024] bf16
{
    __shared__ unsigned short Klds[2 * 64 * 64];
    __shared__ unsigned short Vlds[2 * 64 * 64];
    const int tid  = threadIdx.x;
    const int wave = tid >> 6, lane = tid & 63;
    const int l15  = lane & 15, quad = lane >> 4;
    const int swz  = l15 & 7;
    const int bh   = blockIdx.y;
    const int b_   = bh >> 4, h_ = bh & 15;
    const int q0   = blockIdx.x * 256;

    const unsigned short* Qb = Qp + (size_t)bh * SEQ * DEPTH;
    const unsigned short* Kb = Kp + (size_t)bh * SEQ * DEPTH;
    const unsigned short* Vb = Vtg + (size_t)h_ * DEPTH * MROWS + (size_t)b_ * SEQ;

    const int srow = (wave << 3) + (lane >> 3);
    const int scg  = (lane & 7) ^ ((lane >> 3) & 7);   // swizzled source granule

    const unsigned short* Kg0 = Kb + (size_t)srow * DEPTH + scg * 8;
    const unsigned short* Kg1 = Kb + (size_t)(srow + 32) * DEPTH + scg * 8;
    const unsigned short* Vg0 = Vb + (size_t)srow * MROWS + scg * 8;
    const unsigned short* Vg1 = Vb + (size_t)(srow + 32) * MROWS + scg * 8;

    // Q B-fragments (persistent): lane holds Q[q=16i+l15][d=32kc+quad*8+j]
    bf16x8 qf[4][2];
    #pragma unroll
    for (int i = 0; i < 4; ++i)
        #pragma unroll
        for (int kc = 0; kc < 2; ++kc)
            qf[i][kc] = *(const bf16x8*)(Qb + (size_t)(q0 + wave * 64 + i * 16 + l15) * DEPTH
                                         + kc * 32 + quad * 8);

    // all-ones bf16 A-fragment for the l-sum MFMA
    union { bf16x8 v; unsigned short s[8]; } uo;
    #pragma unroll
    for (int j = 0; j < 8; ++j) uo.s[j] = 0x3F80;
    const bf16x8 ones = uo.v;

    f32x4 Ot[4][4] = {};
    f32x4 lacc[4]  = {};

    auto STAGE = [&](int buf, int kt) {
        unsigned short* KW = &Klds[buf * 4096 + wave * 512];
        unsigned short* VW = &Vlds[buf * 4096 + wave * 512];
        gload16(Kg0 + (size_t)kt * 4096, KW);
        gload16(Kg1 + (size_t)kt * 4096, KW + 2048);
        gload16(Vg0 + kt * 64, VW);
        gload16(Vg1 + kt * 64, VW + 2048);
    };

    STAGE(0, 0);
    asm volatile("s_waitcnt vmcnt(0)" ::: "memory");
    __builtin_amdgcn_s_barrier();

    for (int kt = 0; kt < SEQ / 64; ++kt) {
        const int cur = kt & 1;
        if (kt + 1 < SEQ / 64) STAGE(cur ^ 1, kt + 1);

        const unsigned short* Kc = &Klds[cur * 4096];

        // two 32-key subtiles; subtile `half` covers keys 64kt+32half..+31
        #pragma unroll
        for (int half = 0; half < 2; ++half) {
            // ---- QK^T MFMA cluster (keys 32half..32half+31) ----
            __builtin_amdgcn_s_setprio(1);
            const int r0 = (2 * half) * 16 + l15;
            const int r1 = (2 * half + 1) * 16 + l15;
            bf16x8 ka0 = *(const bf16x8*)&Kc[r0 * 64 + ((quad ^ swz) << 3)];
            bf16x8 ka1 = *(const bf16x8*)&Kc[r0 * 64 + (((4 + quad) ^ swz) << 3)];
            bf16x8 kb0 = *(const bf16x8*)&Kc[r1 * 64 + ((quad ^ swz) << 3)];
            bf16x8 kb1 = *(const bf16x8*)&Kc[r1 * 64 + (((4 + quad) ^ swz) << 3)];
            f32x4 S0[4], S1[4];
            #pragma unroll
            for (int i = 0; i < 4; ++i) {
                S0[i] = f32x4{};
                S0[i] = __builtin_amdgcn_mfma_f32_16x16x32_bf16(ka0, qf[i][0], S0[i], 0, 0, 0);
                S0[i] = __builtin_amdgcn_mfma_f32_16x16x32_bf16(ka1, qf[i][1], S0[i], 0, 0, 0);
                S1[i] = f32x4{};
                S1[i] = __builtin_amdgcn_mfma_f32_16x16x32_bf16(kb0, qf[i][0], S1[i], 0, 0, 0);
                S1[i] = __builtin_amdgcn_mfma_f32_16x16x32_bf16(kb1, qf[i][1], S1[i], 0, 0, 0);
            }
            __builtin_amdgcn_s_setprio(0);

            // ---- softmax: p = exp2(S), pack P B-fragments in-register ----
            bf16x8 pfh[4];
            #pragma unroll
            for (int i = 0; i < 4; ++i) {
                float e0 = __builtin_amdgcn_exp2f(S0[i][0]);
                float e1 = __builtin_amdgcn_exp2f(S0[i][1]);
                float e2 = __builtin_amdgcn_exp2f(S0[i][2]);
                float e3 = __builtin_amdgcn_exp2f(S0[i][3]);
                float e4 = __builtin_amdgcn_exp2f(S1[i][0]);
                float e5 = __builtin_amdgcn_exp2f(S1[i][1]);
                float e6 = __builtin_amdgcn_exp2f(S1[i][2]);
                float e7 = __builtin_amdgcn_exp2f(S1[i][3]);
                union { bf16x8 v; __hip_bfloat162 h[4]; } up;
                up.h[0] = __float22bfloat162_rn(make_float2(e0, e1));
                up.h[1] = __float22bfloat162_rn(make_float2(e2, e3));
                up.h[2] = __float22bfloat162_rn(make_float2(e4, e5));
                up.h[3] = __float22bfloat162_rn(make_float2(e6, e7));
                pfh[i] = up.v;
            }

            // ---- l-sum + PV MFMA cluster ----
            __builtin_amdgcn_s_setprio(1);
            lacc[0] = __builtin_amdgcn_mfma_f32_16x16x32_bf16(ones, pfh[0], lacc[0], 0, 0, 0);
            lacc[1] = __builtin_amdgcn_mfma_f32_16x16x32_bf16(ones, pfh[1], lacc[1], 0, 0, 0);
            lacc[2] = __builtin_amdgcn_mfma_f32_16x16x32_bf16(ones, pfh[2], lacc[2], 0, 0, 0);
            lacc[3] = __builtin_amdgcn_mfma_f32_16x16x32_bf16(ones, pfh[3], lacc[3], 0, 0, 0);
            #pragma unroll
            for (int dd = 0; dd < 4; ++dd) {
                bf16x8 vf = *(const bf16x8*)&Vlds[cur * 4096 +
                            (dd * 16 + l15) * 64 + (((half * 4 + quad) ^ swz) << 3)];
                #pragma unroll
                for (int i = 0; i < 4; ++i)
                    Ot[i][dd] = __builtin_amdgcn_mfma_f32_16x16x32_bf16(vf, pfh[i], Ot[i][dd], 0, 0, 0);
            }
            __builtin_amdgcn_s_setprio(0);
        }

        asm volatile("s_waitcnt vmcnt(0)" ::: "memory");
        __builtin_amdgcn_s_barrier();
    }

    // lacc[i][*] already holds the full denominator for q = i*16+l15
    #pragma unroll
    for (int i = 0; i < 4; ++i) {
        const float inv = 1.0f / lacc[i][0];
        const int row = b_ * SEQ + q0 + wave * 64 + i * 16 + l15;
        #pragma unroll
        for (int dd = 0; dd < 4; ++dd) {
            ushort4 ov;
            ov.x = f32_bf16(Ot[i][dd][0] * inv);
            ov.y = f32_bf16(Ot[i][dd][1] * inv);
            ov.z = f32_bf16(Ot[i][dd][2] * inv);
            ov.w = f32_bf16(Ot[i][dd][3] * inv);
            const int col = h_ * 64 + dd * 16 + quad * 4;
            *(ushort4*)&Op[(size_t)row * NMODEL + col] = ov;
        }
    }
}

// ---------------------------------------------------------------------------
extern "C" void kernel_launch(void* const* d_in, const int* in_sizes, int n_in,
                              void* d_out, int out_size, void* d_ws, size_t ws_size,
                              hipStream_t stream) {
    const float* q  = (const float*)d_in[0];
    const float* k  = (const float*)d_in[1];
    const float* v  = (const float*)d_in[2];
    const float* wq = (const float*)d_in[3];
    const float* bq = (const float*)d_in[4];
    const float* wk = (const float*)d_in[5];
    const float* bk = (const float*)d_in[6];
    const float* wv = (const float*)d_in[7];
    const float* bv = (const float*)d_in[8];
    const float* wd = (const float*)d_in[9];
    const float* bd = (const float*)d_in[10];

    char* ws = (char*)d_ws;
    size_t off = 0;
    auto alloc = [&](size_t bytes) { char* p = ws + off; off += bytes; return p; };
    const size_t ACT = (size_t)MROWS * NMODEL * 2;
    const size_t WGT = (size_t)NMODEL * NMODEL * 2;

    unsigned short* qb   = (unsigned short*)alloc(ACT);
    unsigned short* kb   = (unsigned short*)alloc(ACT);
    unsigned short* vb   = (unsigned short*)alloc(ACT);
    unsigned short* wqb  = (unsigned short*)alloc(WGT);
    unsigned short* wkb  = (unsigned short*)alloc(WGT);
    unsigned short* wvb  = (unsigned short*)alloc(WGT);
    unsigned short* wdb  = (unsigned short*)alloc(WGT);
    unsigned short* Qp   = (unsigned short*)alloc(ACT);
    unsigned short* Kpj  = (unsigned short*)alloc(ACT);
    unsigned short* Vtg  = (unsigned short*)alloc(ACT);   // [H*64, B*S], token-permuted
    unsigned short* attn = (unsigned short*)alloc(ACT);

    const int nAct4 = MROWS * NMODEL / 4;    // 2,097,152 -> 8192 blocks
    const int nWgt4 = NMODEL * NMODEL / 4;   //   262,144 (early-exit above)
    cvt7_kernel<<<dim3(nAct4 / 256, 7), 256, 0, stream>>>(
        q, k, v, wq, wk, wv, wd, qb, kb, vb, wqb, wkb, wvb, wdb, nAct4, nWgt4);

    const float SC = 0.18033688011112042f;   // log2(e)/sqrt(64)
    gemm_qkv<<<dim3(256, 3), 512, 0, stream>>>(qb, wqb, bq, Qp,
                                               kb, wkb, bk, Kpj,
                                               wvb, vb, bv, Vtg, SC);

    attn_fwd<<<dim3(SEQ / 256, 64), 256, 0, stream>>>(Qp, Kpj, Vtg, attn);

    gemm_dense<<<256, 512, 0, stream>>>(attn, wdb, bd, (float*)d_out);
}